// Round 6
// baseline (138.799 us; speedup 1.0000x reference)
//
#include <hip/hip_runtime.h>
#include <math.h>

#define D_FEAT 64
typedef float f32x4 __attribute__((ext_vector_type(4)));

// Edge-parallel CSR row-offset build (unchanged; never in top-5 dispatches).
__global__ void build_starts_kernel(const int* __restrict__ seg,
                                    int* __restrict__ starts,
                                    int nE, int nN) {
    int e = blockIdx.x * blockDim.x + threadIdx.x;
    if (e >= nE) return;
    int s = seg[e];
    int sprev = (e == 0) ? -1 : seg[e - 1];
    for (int v = sprev + 1; v <= s; ++v) starts[v] = e;
    if (e == nE - 1) {
        for (int v = s + 1; v <= nN; ++v) starts[v] = nE;
    }
}

__device__ __forceinline__ int lower_bound_dev(const int* __restrict__ seg,
                                               int nE, int val) {
    int lo = 0, hi = nE;
    while (lo < hi) {
        int mid = (lo + hi) >> 1;
        if (seg[mid] < val) lo = mid + 1; else hi = mid;
    }
    return lo;
}

// Quad-row gather: one wave = 4 groups of 16 lanes. Group g reads row
// idx[k+4q+g], each lane a float4 (features 4*sub..4*sub+3) -> one
// global_load_dwordx4 covers 4 rows = 1KB (vs 256B before; 4x fewer
// instrs, round-4/5 showed we're issue/latency-bound, not BW-bound).
// Segments clamp-padded to mult-of-4 (was 16 -> padding 44%->12%).
// Persistent grid-stride waves with starts-prefetch kill wave churn and
// hide the per-node prologue latency. Cross-group max = 2 shfl_xor
// rounds; lanes 0..15 store one coalesced dwordx4 row.
template<bool USE_STARTS>
__global__ __launch_bounds__(256) void seg_max_kernel(
    const float* __restrict__ x, const int* __restrict__ nbr,
    const int* __restrict__ seg, const int* __restrict__ starts,
    float* __restrict__ out, int nE, int nN, int nWaves) {
    int wid  = blockIdx.x * (blockDim.x >> 6) + (threadIdx.x >> 6);
    int lane = threadIdx.x & 63;
    int g    = lane >> 4;                 // row slot within quad (0..3)
    int sub  = lane & 15;                 // feature quad: 4*sub..4*sub+3
    size_t feat_off = (size_t)sub * 4;    // in floats

    int v = wid;
    if (v >= nN) return;

    int s, e;
    if (USE_STARTS) {
        s = __builtin_amdgcn_readfirstlane(starts[v]);
        e = __builtin_amdgcn_readfirstlane(starts[v + 1]);
    } else {
        s = __builtin_amdgcn_readfirstlane(lower_bound_dev(seg, nE, v));
        e = __builtin_amdgcn_readfirstlane(lower_bound_dev(seg, nE, v + 1));
    }

    while (v < nN) {
        // Prefetch next node's bounds: issued before the gather latency,
        // consumed next iteration -> starts-load off the critical path.
        int vn = v + nWaves;
        int sn = 0, en = 0;
        if (vn < nN) {
            if (USE_STARTS) {
                sn = __builtin_amdgcn_readfirstlane(starts[vn]);
                en = __builtin_amdgcn_readfirstlane(starts[vn + 1]);
            } else {
                sn = __builtin_amdgcn_readfirstlane(lower_bound_dev(seg, nE, vn));
                en = __builtin_amdgcn_readfirstlane(lower_bound_dev(seg, nE, vn + 1));
            }
        }

        f32x4 m;
        if (e > s) {
            m.x = m.y = m.z = m.w = -INFINITY;
            const int eM1 = e - 1;
            for (int k = s; k < e; k += 64) {
                int kc = k + lane;
                kc = (kc < eM1) ? kc : eM1;   // clamp: dups free for max
                int idxv = __builtin_nontemporal_load(nbr + kc);
#pragma unroll
                for (int q = 0; q < 16; ++q) {
                    if (k + 4 * q < e) {      // uniform (SALU) guard per quad
                        int row = __shfl(idxv, 4 * q + g, 64);
                        const f32x4* rp = (const f32x4*)(x + ((size_t)row << 6) + feat_off);
                        f32x4 val = *rp;      // 4 rows/instr, 1KB total
                        m.x = fmaxf(m.x, val.x);
                        m.y = fmaxf(m.y, val.y);
                        m.z = fmaxf(m.z, val.z);
                        m.w = fmaxf(m.w, val.w);
                    }
                }
            }
            // Cross-group reduce: merge the 4 row-slots (lanes sub, sub+16,
            // sub+32, sub+48) -> lanes 0..15 hold the full feature row.
#pragma unroll
            for (int off = 16; off < 64; off <<= 1) {
                f32x4 o;
                o.x = __shfl_xor(m.x, off, 64);
                o.y = __shfl_xor(m.y, off, 64);
                o.z = __shfl_xor(m.z, off, 64);
                o.w = __shfl_xor(m.w, off, 64);
                m.x = fmaxf(m.x, o.x);
                m.y = fmaxf(m.y, o.y);
                m.z = fmaxf(m.z, o.z);
                m.w = fmaxf(m.w, o.w);
            }
        } else {
            m.x = m.y = m.z = m.w = 0.0f;     // empty segment -> zeros
        }

        if (g == 0) {
            __builtin_nontemporal_store(m,
                (f32x4*)(out + (size_t)v * D_FEAT + feat_off));
        }

        v = vn; s = sn; e = en;
    }
}

extern "C" void kernel_launch(void* const* d_in, const int* in_sizes, int n_in,
                              void* d_out, int out_size, void* d_ws, size_t ws_size,
                              hipStream_t stream) {
    const float* x   = (const float*)d_in[0];
    const int*   nbr = (const int*)d_in[1];
    const int*   seg = (const int*)d_in[2];
    float*       out = (float*)d_out;

    int nN = in_sizes[0] / D_FEAT;  // 100000
    int nE = in_sizes[1];           // 1600000

    const int wavesPerBlock = 4;    // 256 threads
    int grid = 2048;                // persistent-ish: 8192 waves, grid-stride
    int nWaves = grid * wavesPerBlock;

    size_t starts_bytes = (size_t)(nN + 1) * sizeof(int);
    if (ws_size >= starts_bytes) {
        int* starts = (int*)d_ws;
        int bgrid = (nE + 255) / 256;
        hipLaunchKernelGGL(build_starts_kernel, dim3(bgrid), dim3(256), 0, stream,
                           seg, starts, nE, nN);
        hipLaunchKernelGGL((seg_max_kernel<true>), dim3(grid), dim3(256), 0, stream,
                           x, nbr, seg, starts, out, nE, nN, nWaves);
    } else {
        hipLaunchKernelGGL((seg_max_kernel<false>), dim3(grid), dim3(256), 0, stream,
                           x, nbr, seg, nullptr, out, nE, nN, nWaves);
    }
}